// Round 9
// baseline (457.548 us; speedup 1.0000x reference)
//
#include <hip/hip_runtime.h>
#include <math.h>

// ---- problem constants ----
#define TT 80
#define BS 8
#define NA 6
#define DMODEL 768
#define DH 192
#define FFD 1024
#define NROWS 640
#define NQKV 2304

typedef __bf16 bf16;
typedef __bf16 bf16x8 __attribute__((ext_vector_type(8)));
typedef float  f32x4  __attribute__((ext_vector_type(4)));

// row stats (sum, sumsq) -> (mean, rstd) with LN eps
__device__ __forceinline__ void row_ms(const float* __restrict__ st, int row,
                                       float& m, float& rs) {
    float s1 = st[row * 2], s2 = st[row * 2 + 1];
    m = s1 * (1.0f / 768.0f);
    float var = s2 * (1.0f / 768.0f) - m * m;
    rs = rsqrtf(var + 1e-5f);
}

// normalize 8 raw bf16 with (m, rs, gamma, beta) -> bf16x8 (as uint4)
__device__ __forceinline__ uint4 norm8(uint4 raw, float m, float rs,
                                       const float* __restrict__ gp,
                                       const float* __restrict__ bp) {
    union { bf16 t[8]; uint4 u; } in, out;
    in.u = raw;
#pragma unroll
    for (int j = 0; j < 8; j++) {
        float a = (float)in.t[j];
        out.t[j] = (bf16)((a - m) * rs * gp[j] + bp[j]);
    }
    return out.u;
}

// ---------------- prep: weight transpose->bf16 + embedding + stats zero -----
// blocks 0..15359: one 32x32 transpose tile each (verified R8).
// blocks 15360..15999: embedding row r (t*8+b) + zero stats rows.
struct TJob { const float* src; bf16* dst; int ldsrc, Kd, n0, k0; };

__global__ __launch_bounds__(256) void prep_k(
        const float* __restrict__ x, const int* __restrict__ y,
        const int* __restrict__ ind_map,
        const float* __restrict__ skel_W, const float* __restrict__ skel_b,
        const float* __restrict__ muQ, const float* __restrict__ sigQ,
        const float* __restrict__ Wq, const float* __restrict__ Wk,
        const float* __restrict__ Wv, const float* __restrict__ Wo,
        const float* __restrict__ W1, const float* __restrict__ W2,
        bf16* __restrict__ qkvT, bf16* __restrict__ woT,
        bf16* __restrict__ w1T, bf16* __restrict__ w2T,
        float* __restrict__ h, bf16* __restrict__ h0B,
        float* __restrict__ stats) {
    __shared__ float tile[32][33];
    __shared__ float xrow[152];
    int bid = blockIdx.x, tid = threadIdx.x;
    if (bid < 15360) {
        TJob J;
        int l = bid / 3840, r = bid % 3840;
        if (r < 1728) {                             // QKV: K=768, N=2304
            int kt = r % 24, nt = r / 24;
            J.k0 = kt * 32; J.n0 = nt * 32; J.Kd = 768; J.ldsrc = 768;
            J.dst = qkvT + (size_t)l * NQKV * DMODEL;
            if (J.n0 < 768)       { J.src = Wq + (size_t)l * 589824 + J.n0; }
            else if (J.n0 < 1536) { J.src = Wk + (size_t)l * 589824 + (J.n0 - 768); }
            else                  { J.src = Wv + (size_t)l * 589824 + (J.n0 - 1536); }
        } else if (r < 2304) {                      // Wo: 768x768
            int r2 = r - 1728; int kt = r2 % 24, nt = r2 / 24;
            J.k0 = kt * 32; J.n0 = nt * 32; J.Kd = 768; J.ldsrc = 768;
            J.src = Wo + (size_t)l * 589824 + J.n0;
            J.dst = woT + (size_t)l * 589824;
        } else if (r < 3072) {                      // W1: K=768, N=1024
            int r2 = r - 2304; int kt = r2 % 24, nt = r2 / 24;
            J.k0 = kt * 32; J.n0 = nt * 32; J.Kd = 768; J.ldsrc = 1024;
            J.src = W1 + (size_t)l * 786432 + J.n0;
            J.dst = w1T + (size_t)l * 786432;
        } else {                                    // W2: K=1024, N=768
            int r2 = r - 3072; int kt = r2 % 32, nt = r2 / 32;
            J.k0 = kt * 32; J.n0 = nt * 32; J.Kd = 1024; J.ldsrc = 768;
            J.src = W2 + (size_t)l * 786432 + J.n0;
            J.dst = w2T + (size_t)l * 786432;
        }
        int tx = tid & 31, ty = tid >> 5;
#pragma unroll
        for (int i = 0; i < 4; i++) {
            int rr = ty + 8 * i;
            tile[rr][tx] = J.src[(size_t)(J.k0 + rr) * J.ldsrc + tx];
        }
        __syncthreads();
#pragma unroll
        for (int i = 0; i < 4; i++) {
            int rr = ty + 8 * i;
            J.dst[(size_t)(J.n0 + rr) * J.Kd + J.k0 + tx] = (bf16)tile[tx][rr];
        }
    } else {
        int r = bid - 15360;
        int t = r >> 3, b = r & 7;
        int c = tid;
        // zero stats rows for this row index (all 4 layers x {stats1,stats2})
        if (c < 16) {
            int arr = c >> 3, l = (c >> 1) & 3, j = c & 1;
            stats[arr * 5120 + l * 1280 + r * 2 + j] = 0.0f;
        }
        if (c < 150) xrow[c] = x[(b * 150 + c) * TT + t];
        __syncthreads();
        float acc = skel_b[c];
        for (int jf = 0; jf < 150; jf++) acc += xrow[jf] * skel_W[jf * 256 + c];
        int ind_t = ind_map[t * 8 + b];
        int yb = y[b * NA + ind_t];
        float cm = muQ[yb * 256 + c];
        float cs = sigQ[yb * 256 + c];
        int start = (t == 0) ? 0 : (t + 2);
        float div = expf((float)(c & ~1) * (-9.210340371976184f / 256.0f));
        float p0, p1, p2;
        if (c & 1) {
            p0 = cosf((float)start * div);
            p1 = cosf((float)(start + 1) * div);
            p2 = cosf((float)(start + 2) * div);
        } else {
            p0 = sinf((float)start * div);
            p1 = sinf((float)(start + 1) * div);
            p2 = sinf((float)(start + 2) * div);
        }
        float* hr = h + (size_t)r * DMODEL;
        float v0 = cm + p0, v1 = cs + p1, v2 = acc + p2;
        hr[c] = v0; hr[c + 256] = v1; hr[c + 512] = v2;
        bf16* hb = h0B + (size_t)r * DMODEL;
        hb[c] = (bf16)v0; hb[c + 256] = (bf16)v1; hb[c + 512] = (bf16)v2;
    }
}

// ---------------- bf16 MFMA GEMM: 32x32 tile, 128 threads (2 waves) ---------
// Small tiles -> 480-1440 blocks -> 2-5 blocks/CU; cross-block TLP hides the
// barrier-serialized staging (R8 post-mortem: 64x64 grids left half the CUs
// idle; GEMMs ran ~100 TF occupancy-bound).
// ANORM=1: A is RAW bf16 + row stats + LN params, normalized inline during
// LDS staging (A-traffic halved vs R8's f32 path).
// EPI 0: QKV epilogue (col-segmented bias, elu+1 on Q/K, bf16 out)
// EPI 1: bias + residual (RNORM: normalize resid inline) -> f32 out + raw
//        bf16 out + per-row (sum,sumsq) atomics into stOut
// EPI 2: bias + relu, bf16 out
template <int EPI, int ANORM, int RNORM>
__global__ __launch_bounds__(128) void gemm_mfma(
        const bf16* __restrict__ Ab,
        const float* __restrict__ stA, const float* __restrict__ gA,
        const float* __restrict__ bA,
        const bf16* __restrict__ Bt,
        const float* __restrict__ bias_q, const float* __restrict__ bias_k,
        const float* __restrict__ bias_v,
        const float* __restrict__ residF, const float* __restrict__ stR,
        const float* __restrict__ gR, const float* __restrict__ bR,
        float* __restrict__ outF, bf16* __restrict__ outB,
        float* __restrict__ stOut, int N, int K) {
    __shared__ __attribute__((aligned(16))) bf16 As0[32][40];
    __shared__ __attribute__((aligned(16))) bf16 As1[32][40];
    __shared__ __attribute__((aligned(16))) bf16 Bs0[32][40];
    __shared__ __attribute__((aligned(16))) bf16 Bs1[32][40];
    int tid = threadIdx.x;
    int m0 = blockIdx.y * 32, n0 = blockIdx.x * 32;
    int w = tid >> 6, l = tid & 63;        // w in {0,1}
    int lm = l & 15, lq = l >> 4;
    int sr = tid >> 2;                     // 0..31
    int sk = (tid & 3) * 8;
    int arow = m0 + sr;
    const bf16* Arow = &Ab[(size_t)arow * K];
    const bf16* Brow = &Bt[(size_t)(n0 + sr) * K];
    f32x4 acc[2] = {};
    float mA = 0.f, rsA = 0.f;
    if (ANORM) row_ms(stA, arow, mA, rsA);
    // prefetch chunk 0
    uint4 a0 = *(const uint4*)&Arow[sk];
    uint4 a1 = *(const uint4*)&Arow[32 + sk];
    uint4 b0 = *(const uint4*)&Brow[sk];
    uint4 b1 = *(const uint4*)&Brow[32 + sk];
    for (int k0 = 0; k0 < K; k0 += 64) {
        __syncthreads();
        if (ANORM) {
            *(uint4*)&As0[sr][sk] = norm8(a0, mA, rsA, gA + k0 + sk, bA + k0 + sk);
            *(uint4*)&As1[sr][sk] = norm8(a1, mA, rsA, gA + k0 + 32 + sk, bA + k0 + 32 + sk);
        } else {
            *(uint4*)&As0[sr][sk] = a0;
            *(uint4*)&As1[sr][sk] = a1;
        }
        *(uint4*)&Bs0[sr][sk] = b0;
        *(uint4*)&Bs1[sr][sk] = b1;
        __syncthreads();
        int k2 = k0 + 64; if (k2 >= K) k2 = 0;   // tail: harmless re-read
        a0 = *(const uint4*)&Arow[k2 + sk];
        a1 = *(const uint4*)&Arow[k2 + 32 + sk];
        b0 = *(const uint4*)&Brow[k2 + sk];
        b1 = *(const uint4*)&Brow[k2 + 32 + sk];
        bf16x8 af0 = *(bf16x8*)&As0[w * 16 + lm][lq * 8];
        bf16x8 af1 = *(bf16x8*)&As1[w * 16 + lm][lq * 8];
#pragma unroll
        for (int nb = 0; nb < 2; nb++) {
            bf16x8 bfr = *(bf16x8*)&Bs0[nb * 16 + lm][lq * 8];
            acc[nb] = __builtin_amdgcn_mfma_f32_16x16x32_bf16(af0, bfr, acc[nb], 0, 0, 0);
        }
#pragma unroll
        for (int nb = 0; nb < 2; nb++) {
            bf16x8 bfr = *(bf16x8*)&Bs1[nb * 16 + lm][lq * 8];
            acc[nb] = __builtin_amdgcn_mfma_f32_16x16x32_bf16(af1, bfr, acc[nb], 0, 0, 0);
        }
    }
    // ---- epilogue ----
    if (EPI == 1) {
        float mR4[4], rsR4[4];
        if (RNORM) {
#pragma unroll
            for (int r = 0; r < 4; r++)
                row_ms(stR, m0 + w * 16 + lq * 4 + r, mR4[r], rsR4[r]);
        }
        float s1[4] = {0.f, 0.f, 0.f, 0.f}, s2[4] = {0.f, 0.f, 0.f, 0.f};
#pragma unroll
        for (int nb = 0; nb < 2; nb++) {
            int col = n0 + nb * 16 + lm;
            float bia = bias_q[col];
            float gc = 0.f, bc = 0.f;
            if (RNORM) { gc = gR[col]; bc = bR[col]; }
#pragma unroll
            for (int r = 0; r < 4; r++) {
                int row = m0 + w * 16 + lq * 4 + r;
                float rv = residF[(size_t)row * N + col];
                if (RNORM) rv = (rv - mR4[r]) * rsR4[r] * gc + bc;
                float v = acc[nb][r] + bia + rv;
                outF[(size_t)row * N + col] = v;
                outB[(size_t)row * N + col] = (bf16)v;   // raw copy for ANORM consumers
                s1[r] += v; s2[r] += v * v;
            }
        }
        // reduce over lm (16 lanes hold this block's 32 cols of each row)
#pragma unroll
        for (int mk = 1; mk < 16; mk <<= 1) {
#pragma unroll
            for (int r = 0; r < 4; r++) {
                s1[r] += __shfl_xor(s1[r], mk, 64);
                s2[r] += __shfl_xor(s2[r], mk, 64);
            }
        }
        if (lm == 0) {
#pragma unroll
            for (int r = 0; r < 4; r++) {
                int row = m0 + w * 16 + lq * 4 + r;
                atomicAdd(&stOut[row * 2],     s1[r]);
                atomicAdd(&stOut[row * 2 + 1], s2[r]);
            }
        }
    } else {
#pragma unroll
        for (int nb = 0; nb < 2; nb++) {
            int col = n0 + nb * 16 + lm;
            float bia; bool do_elu = false;
            if (EPI == 0) {
                if (col < 768)       { bia = bias_q[col];        do_elu = true; }
                else if (col < 1536) { bia = bias_k[col - 768];  do_elu = true; }
                else                 { bia = bias_v[col - 1536]; }
            } else {
                bia = bias_q[col];
            }
#pragma unroll
            for (int r = 0; r < 4; r++) {
                int row = m0 + w * 16 + lq * 4 + r;
                float v = acc[nb][r] + bia;
                if (EPI == 0) {
                    if (do_elu) v = (v > 0.0f) ? (v + 1.0f) : expf(v);
                    outB[(size_t)row * N + col] = (bf16)v;
                } else {
                    outB[(size_t)row * N + col] = (bf16)fmaxf(v, 0.0f);
                }
            }
        }
    }
}

// ---------------- causal linear attention: 96 blocks (x3 PV split) ----------
// Verified numerically R8.
__global__ __launch_bounds__(320) void attn_k(
        const bf16* __restrict__ qkvB, bf16* __restrict__ att) {
    __shared__ __attribute__((aligned(16))) char smem[64000];
    bf16* Qs = (bf16*)smem;            // [80][200]
    bf16* Ks = (bf16*)(smem + 32000);  // [80][200]
    bf16* Aij = (bf16*)smem;           // [80][104]  (overlays Qs after phase 1)
    bf16* VT = (bf16*)(smem + 16640);  // [192][104] (overlays Ks)
    int bh = blockIdx.x / 3, part = blockIdx.x % 3;
    int bb = bh >> 2, hd = bh & 3;
    int tid = threadIdx.x;
    int w = tid >> 6, l = tid & 63;
    int lm = l & 15, lq = l >> 4;

    uint4 vreg[6];
#pragma unroll
    for (int u = 0; u < 6; u++) {
        int c = tid + 320 * u;
        int t = c / 24, cc = c % 24;
        int d0 = cc * 8;
        size_t g = (size_t)(t * 8 + bb) * NQKV + hd * DH + d0;
        uint4 qv = *(const uint4*)&qkvB[g];
        uint4 kv = *(const uint4*)&qkvB[g + 768];
        vreg[u]  = *(const uint4*)&qkvB[g + 1536];
        *(uint4*)&Qs[t * 200 + d0] = qv;
        *(uint4*)&Ks[t * 200 + d0] = kv;
    }
    __syncthreads();

    f32x4 acc[5] = {};
#pragma unroll
    for (int k0 = 0; k0 < 192; k0 += 32) {
        bf16x8 af = *(bf16x8*)&Qs[(w * 16 + lm) * 200 + lq * 8 + k0];
#pragma unroll
        for (int nb = 0; nb < 5; nb++) {
            bf16x8 bfr = *(bf16x8*)&Ks[(nb * 16 + lm) * 200 + lq * 8 + k0];
            acc[nb] = __builtin_amdgcn_mfma_f32_16x16x32_bf16(af, bfr, acc[nb], 0, 0, 0);
        }
    }
    float mval[5][4];
    float rs[4] = {0.f, 0.f, 0.f, 0.f};
#pragma unroll
    for (int nb = 0; nb < 5; nb++)
#pragma unroll
        for (int r = 0; r < 4; r++) {
            int t = w * 16 + lq * 4 + r, tau = nb * 16 + lm;
            float v = (tau <= t) ? acc[nb][r] : 0.0f;
            mval[nb][r] = v;
            rs[r] += v;
        }
#pragma unroll
    for (int mk = 1; mk < 16; mk <<= 1)
#pragma unroll
        for (int r = 0; r < 4; r++) rs[r] += __shfl_xor(rs[r], mk, 64);
    float inv[4];
#pragma unroll
    for (int r = 0; r < 4; r++) inv[r] = 1.0f / (rs[r] + 1e-6f);

    __syncthreads();

#pragma unroll
    for (int nb = 0; nb < 5; nb++)
#pragma unroll
        for (int r = 0; r < 4; r++)
            Aij[(w * 16 + lq * 4 + r) * 104 + nb * 16 + lm] = (bf16)mval[nb][r];
    *(uint2*)&Aij[(tid >> 2) * 104 + 80 + (tid & 3) * 4] = make_uint2(0u, 0u);
#pragma unroll
    for (int u = 0; u < 6; u++) {
        int c = tid + 320 * u;
        int t = c / 24, cc = c % 24;
        int d0 = cc * 8;
        bf16 tmp8[8];
        *(uint4*)tmp8 = vreg[u];
#pragma unroll
        for (int j = 0; j < 8; j++) VT[(d0 + j) * 104 + t] = tmp8[j];
    }
    if (tid < 192) {
        *(uint4*)&VT[tid * 104 + 80] = make_uint4(0u, 0u, 0u, 0u);
        *(uint4*)&VT[tid * 104 + 88] = make_uint4(0u, 0u, 0u, 0u);
    }
    __syncthreads();

#pragma unroll 1
    for (int nc = part * 4; nc < part * 4 + 4; nc++) {
        f32x4 a2 = {};
#pragma unroll
        for (int k0 = 0; k0 < 96; k0 += 32) {
            bf16x8 af = *(bf16x8*)&Aij[(w * 16 + lm) * 104 + lq * 8 + k0];
            bf16x8 bfr = *(bf16x8*)&VT[(nc * 16 + lm) * 104 + lq * 8 + k0];
            a2 = __builtin_amdgcn_mfma_f32_16x16x32_bf16(af, bfr, a2, 0, 0, 0);
        }
#pragma unroll
        for (int r = 0; r < 4; r++) {
            int t = w * 16 + lq * 4 + r;
            att[(size_t)(t * 8 + bb) * DMODEL + hd * DH + nc * 16 + lm] =
                (bf16)(a2[r] * inv[r]);
        }
    }
}

// ---------------- final: inline ln2(tmp2) then lnf, gather outputs ----------
__device__ __forceinline__ float block_reduce_sum256(float v, float* sm4) {
#pragma unroll
    for (int off = 32; off > 0; off >>= 1) v += __shfl_down(v, off, 64);
    int lane = threadIdx.x & 63, wid = threadIdx.x >> 6;
    if (lane == 0) sm4[wid] = v;
    __syncthreads();
    float r = sm4[0] + sm4[1] + sm4[2] + sm4[3];
    __syncthreads();
    return r;
}

__global__ __launch_bounds__(256) void final_k(
        const float* __restrict__ tmp2, const float* __restrict__ st2,
        const float* __restrict__ g2, const float* __restrict__ b2,
        const int* __restrict__ act_ts,
        const float* __restrict__ gf, const float* __restrict__ bf_,
        float* __restrict__ out) {
    __shared__ float sm4[4];
    int ba = blockIdx.x;
    int b = ba / NA;
    int ts = act_ts[ba];
    int t = ts - 1; if (t < 0) t = 0;
    int row = t * 8 + b;
    const float* xr = tmp2 + (size_t)row * DMODEL;
    int c = threadIdx.x;
    float m2, rs2;
    row_ms(st2, row, m2, rs2);
    float x0 = (xr[c]       - m2) * rs2 * g2[c]       + b2[c];
    float x1 = (xr[c + 256] - m2) * rs2 * g2[c + 256] + b2[c + 256];
    float x2 = (xr[c + 512] - m2) * rs2 * g2[c + 512] + b2[c + 512];
    float m = block_reduce_sum256(x0 + x1 + x2, sm4) * (1.0f / 768.0f);
    float d0 = x0 - m, d1 = x1 - m, d2 = x2 - m;
    float v = block_reduce_sum256(d0 * d0 + d1 * d1 + d2 * d2, sm4) * (1.0f / 768.0f);
    float r = rsqrtf(v + 1e-5f);
    out[ba * 256 + c]            = d0 * r * gf[c] + bf_[c];                 // mu
    out[48 * 256 + ba * 256 + c] = d1 * r * gf[c + 256] + bf_[c + 256];     // logvar
}

extern "C" void kernel_launch(void* const* d_in, const int* in_sizes, int n_in,
                              void* d_out, int out_size, void* d_ws, size_t ws_size,
                              hipStream_t stream) {
    const float* x       = (const float*)d_in[0];
    const int*   y       = (const int*)d_in[1];
    const int*   ind_map = (const int*)d_in[2];
    const int*   act_ts  = (const int*)d_in[3];
    const float* skel_W  = (const float*)d_in[4];
    const float* skel_b  = (const float*)d_in[5];
    const float* muQ     = (const float*)d_in[6];
    const float* sigQ    = (const float*)d_in[7];
    const float* Wq = (const float*)d_in[8];   const float* bq = (const float*)d_in[9];
    const float* Wk = (const float*)d_in[10];  const float* bk = (const float*)d_in[11];
    const float* Wv = (const float*)d_in[12];  const float* bv = (const float*)d_in[13];
    const float* Wo = (const float*)d_in[14];  const float* bo = (const float*)d_in[15];
    const float* W1 = (const float*)d_in[16];  const float* b1 = (const float*)d_in[17];
    const float* W2 = (const float*)d_in[18];  const float* b2 = (const float*)d_in[19];
    const float* ln1_g = (const float*)d_in[20]; const float* ln1_b = (const float*)d_in[21];
    const float* ln2_g = (const float*)d_in[22]; const float* ln2_b = (const float*)d_in[23];
    const float* lnf_g = (const float*)d_in[24]; const float* lnf_b = (const float*)d_in[25];
    float* out = (float*)d_out;

    // ---- workspace layout (all 16B aligned) ----
    char* p = (char*)d_ws;
    const size_t R = (size_t)NROWS * DMODEL;
    float* h     = (float*)p; p += R * 4;                       // embed out (f32)
    float* tmp1  = (float*)p; p += R * 4;                       // pre-LN1 (f32)
    float* tmp2  = (float*)p; p += R * 4;                       // pre-LN2 (f32)
    float* stats = (float*)p; p += 10240 * 4;                   // [2][4][640][2]
    bf16* h0B    = (bf16*)p;  p += R * 2;
    bf16* tmp1B  = (bf16*)p;  p += R * 2;                       // raw bf16 copy of tmp1
    bf16* tmp2B  = (bf16*)p;  p += R * 2;                       // raw bf16 copy of tmp2
    bf16* qkvB   = (bf16*)p;  p += (size_t)NROWS * NQKV * 2;
    bf16* attB   = (bf16*)p;  p += R * 2;
    bf16* ffn1B  = (bf16*)p;  p += (size_t)NROWS * FFD * 2;
    bf16* qkvT   = (bf16*)p;  p += (size_t)4 * NQKV * DMODEL * 2;
    bf16* woT    = (bf16*)p;  p += (size_t)4 * DMODEL * DMODEL * 2;
    bf16* w1T    = (bf16*)p;  p += (size_t)4 * FFD * DMODEL * 2;
    bf16* w2T    = (bf16*)p;  p += (size_t)4 * DMODEL * FFD * 2;

    // 1. transpose + embed + stats zero (self-reinitializing each replay)
    prep_k<<<16000, 256, 0, stream>>>(x, y, ind_map, skel_W, skel_b, muQ, sigQ,
                                      Wq, Wk, Wv, Wo, W1, W2,
                                      qkvT, woT, w1T, w2T, h, h0B, stats);

    dim3 gQKV(NQKV / 32, 20);   // 72 x 20 = 1440 blocks
    dim3 g768(24, 20);          // 480 blocks
    dim3 g1024(32, 20);         // 640 blocks
    for (int l = 0; l < 4; l++) {
        const bf16* qkvTl = qkvT + (size_t)l * NQKV * DMODEL;
        const bf16* woTl  = woT  + (size_t)l * DMODEL * DMODEL;
        const bf16* w1Tl  = w1T  + (size_t)l * FFD * DMODEL;
        const bf16* w2Tl  = w2T  + (size_t)l * DMODEL * FFD;
        float* st1 = stats + l * 1280;
        float* st2 = stats + 5120 + l * 1280;
        const float* st2p = stats + 5120 + (l - 1) * 1280;       // prev layer
        const float* g2p = ln2_g + (l - 1) * DMODEL;
        const float* b2p = ln2_b + (l - 1) * DMODEL;

        // QKV: A = h0 (l=0) or norm2(tmp2B_prev) inline
        if (l == 0)
            gemm_mfma<0, 0, 0><<<gQKV, 128, 0, stream>>>(
                h0B, nullptr, nullptr, nullptr, qkvTl,
                bq, bk, bv,
                nullptr, nullptr, nullptr, nullptr,
                nullptr, qkvB, nullptr, NQKV, DMODEL);
        else
            gemm_mfma<0, 1, 0><<<gQKV, 128, 0, stream>>>(
                tmp2B, st2p, g2p, b2p, qkvTl,
                bq + l * DMODEL, bk + l * DMODEL, bv + l * DMODEL,
                nullptr, nullptr, nullptr, nullptr,
                nullptr, qkvB, nullptr, NQKV, DMODEL);

        attn_k<<<96, 320, 0, stream>>>(qkvB, attB);

        // Wo: tmp1 = att@Wo + bo + resid, + raw bf16 copy + stats1 atomics
        if (l == 0)
            gemm_mfma<1, 0, 0><<<g768, 128, 0, stream>>>(
                attB, nullptr, nullptr, nullptr, woTl,
                bo, nullptr, nullptr,
                h, nullptr, nullptr, nullptr,
                tmp1, tmp1B, st1, DMODEL, DMODEL);
        else
            gemm_mfma<1, 0, 1><<<g768, 128, 0, stream>>>(
                attB, nullptr, nullptr, nullptr, woTl,
                bo + l * DMODEL, nullptr, nullptr,
                tmp2, st2p, g2p, b2p,
                tmp1, tmp1B, st1, DMODEL, DMODEL);

        // FFN1: A = norm1(tmp1B) inline; relu -> ffn1B
        gemm_mfma<2, 1, 0><<<g1024, 128, 0, stream>>>(
            tmp1B, st1, ln1_g + l * DMODEL, ln1_b + l * DMODEL, w1Tl,
            b1 + l * FFD, nullptr, nullptr,
            nullptr, nullptr, nullptr, nullptr,
            nullptr, ffn1B, nullptr, FFD, DMODEL);

        // FFN2: tmp2 = ffn1@W2 + b2 + norm1(tmp1), + raw bf16 + stats2 atomics
        gemm_mfma<1, 0, 1><<<g768, 128, 0, stream>>>(
            ffn1B, nullptr, nullptr, nullptr, w2Tl,
            b2 + l * DMODEL, nullptr, nullptr,
            tmp1, st1, ln1_g + l * DMODEL, ln1_b + l * DMODEL,
            tmp2, tmp2B, st2, DMODEL, FFD);
    }

    final_k<<<48, 256, 0, stream>>>(tmp2, stats + 5120 + 3 * 1280,
                                    ln2_g + 3 * DMODEL, ln2_b + 3 * DMODEL,
                                    act_ts, lnf_g, lnf_b, out);
}

// Round 10
// 418.815 us; speedup vs baseline: 1.0925x; 1.0925x over previous
//
#include <hip/hip_runtime.h>
#include <math.h>

// Problem constants
#define TT 80
#define BS 8
#define NA 6
#define DMODEL 768
#define NH 4
#define DH 192
#define FFD 1024
#define NROWS (TT*BS)   // 640
#define NQKV (3*DMODEL) // 2304

typedef __bf16 bf16;
typedef __bf16 bf16x8 __attribute__((ext_vector_type(8)));
typedef float  f32x4  __attribute__((ext_vector_type(4)));

// ---------------- block reduce (256 threads, 4 waves of 64) ----------------
__device__ __forceinline__ float block_reduce_sum256(float v, float* sm4) {
#pragma unroll
    for (int off = 32; off > 0; off >>= 1) v += __shfl_down(v, off, 64);
    int lane = threadIdx.x & 63, wid = threadIdx.x >> 6;
    if (lane == 0) sm4[wid] = v;
    __syncthreads();
    float r = sm4[0] + sm4[1] + sm4[2] + sm4[3];
    __syncthreads();
    return r;
}

// ---------------- prep: ALL weight transposes + embedding (one dispatch) ----
// blocks 0..15359: one 32x32 transpose tile each (decode verified R2..R9).
// blocks 15360..15999: embedding row r = t*8+b (baseline embed_k body).
__global__ __launch_bounds__(256) void prep_k(
        const float* __restrict__ x, const int* __restrict__ y,
        const int* __restrict__ ind_map,
        const float* __restrict__ skel_W, const float* __restrict__ skel_b,
        const float* __restrict__ muQ, const float* __restrict__ sigQ,
        const float* __restrict__ Wq, const float* __restrict__ Wk,
        const float* __restrict__ Wv, const float* __restrict__ Wo,
        const float* __restrict__ W1, const float* __restrict__ W2,
        bf16* __restrict__ qkvT, bf16* __restrict__ woT,
        bf16* __restrict__ w1T, bf16* __restrict__ w2T,
        float* __restrict__ h0, bf16* __restrict__ h0b) {
    __shared__ float tile[32][33];
    __shared__ float xrow[152];
    int bid = blockIdx.x, tid = threadIdx.x;
    if (bid < 15360) {
        const float* src; bf16* dst; int ldsrc, Kd, n0, k0;
        int l = bid / 3840, r = bid % 3840;
        if (r < 1728) {                             // QKV: K=768, N=2304
            int kt = r % 24, nt = r / 24;
            k0 = kt * 32; n0 = nt * 32; Kd = 768; ldsrc = 768;
            dst = qkvT + (size_t)l * NQKV * DMODEL;
            if (n0 < 768)       { src = Wq + (size_t)l * 589824 + n0; }
            else if (n0 < 1536) { src = Wk + (size_t)l * 589824 + (n0 - 768); }
            else                { src = Wv + (size_t)l * 589824 + (n0 - 1536); }
        } else if (r < 2304) {                      // Wo: 768x768
            int r2 = r - 1728; int kt = r2 % 24, nt = r2 / 24;
            k0 = kt * 32; n0 = nt * 32; Kd = 768; ldsrc = 768;
            src = Wo + (size_t)l * 589824 + n0;
            dst = woT + (size_t)l * 589824;
        } else if (r < 3072) {                      // W1: K=768, N=1024
            int r2 = r - 2304; int kt = r2 % 24, nt = r2 / 24;
            k0 = kt * 32; n0 = nt * 32; Kd = 768; ldsrc = 1024;
            src = W1 + (size_t)l * 786432 + n0;
            dst = w1T + (size_t)l * 786432;
        } else {                                    // W2: K=1024, N=768
            int r2 = r - 3072; int kt = r2 % 32, nt = r2 / 32;
            k0 = kt * 32; n0 = nt * 32; Kd = 1024; ldsrc = 768;
            src = W2 + (size_t)l * 786432 + n0;
            dst = w2T + (size_t)l * 786432;
        }
        int tx = tid & 31, ty = tid >> 5;
#pragma unroll
        for (int i = 0; i < 4; i++) {
            int rr = ty + 8 * i;
            tile[rr][tx] = src[(size_t)(k0 + rr) * ldsrc + tx];
        }
        __syncthreads();
#pragma unroll
        for (int i = 0; i < 4; i++) {
            int rr = ty + 8 * i;
            dst[(size_t)(n0 + rr) * Kd + k0 + tx] = (bf16)tile[tx][rr];
        }
    } else {
        int r = bid - 15360;
        int t = r >> 3, b = r & 7;
        int c = tid;
        if (c < 150) xrow[c] = x[(b * 150 + c) * TT + t];
        __syncthreads();
        float acc = skel_b[c];
        for (int jf = 0; jf < 150; jf++) acc += xrow[jf] * skel_W[jf * 256 + c];
        int ind_t = ind_map[t * 8 + b];
        int yb = y[b * NA + ind_t];
        float cm = muQ[yb * 256 + c];
        float cs = sigQ[yb * 256 + c];
        int start = (t == 0) ? 0 : (t + 2);
        float div = expf((float)(c & ~1) * (-9.210340371976184f / 256.0f));
        float p0, p1, p2;
        if (c & 1) {
            p0 = cosf((float)start * div);
            p1 = cosf((float)(start + 1) * div);
            p2 = cosf((float)(start + 2) * div);
        } else {
            p0 = sinf((float)start * div);
            p1 = sinf((float)(start + 1) * div);
            p2 = sinf((float)(start + 2) * div);
        }
        float* hr = h0 + (size_t)r * DMODEL;
        float v0 = cm + p0, v1 = cs + p1, v2 = acc + p2;
        hr[c] = v0; hr[c + 256] = v1; hr[c + 512] = v2;
        bf16* hb = h0b + (size_t)r * DMODEL;
        hb[c] = (bf16)v0; hb[c + 256] = (bf16)v1; hb[c + 512] = (bf16)v2;
    }
}

// ---------------- bf16 MFMA GEMM: tile 64x64, 256 threads (baseline) --------
// K-loop pipelined: register prefetch of next chunk issued right after the
// LDS-write barrier so global (L2) latency overlaps MFMA+ds_read.
// A [M,K] row-major bf16; Bt [N,K] row-major bf16.  K % 64 == 0.
// EPI: 0 = QKV (bias by col segment, elu+1 on cols<1536, bf16 out)
//      1 = bias + f32 resid, f32 out
//      2 = bias + relu, bf16 out
template <int EPI>
__global__ __launch_bounds__(256) void gemm_mfma(
        const bf16* __restrict__ A, const bf16* __restrict__ Bt,
        const float* __restrict__ bias_q, const float* __restrict__ bias_k,
        const float* __restrict__ bias_v, const float* __restrict__ resid,
        float* __restrict__ outF, bf16* __restrict__ outB,
        int M, int N, int K) {
    __shared__ __attribute__((aligned(16))) bf16 As0[64][40];
    __shared__ __attribute__((aligned(16))) bf16 As1[64][40];
    __shared__ __attribute__((aligned(16))) bf16 Bs0[64][40];
    __shared__ __attribute__((aligned(16))) bf16 Bs1[64][40];
    int tid = threadIdx.x;
    int m0 = blockIdx.y * 64, n0 = blockIdx.x * 64;
    int w = tid >> 6;
    int l = tid & 63;
    int lm = l & 15, lq = l >> 4;
    int sr = tid >> 2;          // staging row 0..63
    int sk = (tid & 3) * 8;     // staging k offset within 32-chunk
    const bf16* Arow = &A[(size_t)(m0 + sr) * K];
    const bf16* Brow = &Bt[(size_t)(n0 + sr) * K];
    f32x4 acc[4] = {};
    // prefetch chunk 0
    uint4 a0 = *(const uint4*)&Arow[sk];
    uint4 a1 = *(const uint4*)&Arow[32 + sk];
    uint4 b0 = *(const uint4*)&Brow[sk];
    uint4 b1 = *(const uint4*)&Brow[32 + sk];
    for (int k0 = 0; k0 < K; k0 += 64) {
        __syncthreads();
        *(uint4*)&As0[sr][sk] = a0;
        *(uint4*)&As1[sr][sk] = a1;
        *(uint4*)&Bs0[sr][sk] = b0;
        *(uint4*)&Bs1[sr][sk] = b1;
        __syncthreads();
        int k2 = k0 + 64; if (k2 >= K) k2 = 0;      // tail: harmless re-read
        a0 = *(const uint4*)&Arow[k2 + sk];
        a1 = *(const uint4*)&Arow[k2 + 32 + sk];
        b0 = *(const uint4*)&Brow[k2 + sk];
        b1 = *(const uint4*)&Brow[k2 + 32 + sk];
        bf16x8 af0 = *(bf16x8*)&As0[w * 16 + lm][lq * 8];
        bf16x8 af1 = *(bf16x8*)&As1[w * 16 + lm][lq * 8];
#pragma unroll
        for (int nb = 0; nb < 4; nb++) {
            bf16x8 bf0 = *(bf16x8*)&Bs0[nb * 16 + lm][lq * 8];
            acc[nb] = __builtin_amdgcn_mfma_f32_16x16x32_bf16(af0, bf0, acc[nb], 0, 0, 0);
        }
#pragma unroll
        for (int nb = 0; nb < 4; nb++) {
            bf16x8 bf1 = *(bf16x8*)&Bs1[nb * 16 + lm][lq * 8];
            acc[nb] = __builtin_amdgcn_mfma_f32_16x16x32_bf16(af1, bf1, acc[nb], 0, 0, 0);
        }
    }
#pragma unroll
    for (int nb = 0; nb < 4; nb++) {
        int col = n0 + nb * 16 + lm;
        float b;
        bool do_elu = false;
        if (EPI == 0) {
            if (col < 768)       { b = bias_q[col];        do_elu = true; }
            else if (col < 1536) { b = bias_k[col - 768];  do_elu = true; }
            else                 { b = bias_v[col - 1536]; }
        } else {
            b = bias_q[col];
        }
#pragma unroll
        for (int r = 0; r < 4; r++) {
            int row = m0 + w * 16 + lq * 4 + r;
            float v = acc[nb][r] + b;
            if (EPI == 0) {
                if (do_elu) v = (v > 0.0f) ? (v + 1.0f) : expf(v);
                outB[(size_t)row * N + col] = (bf16)v;
            } else if (EPI == 1) {
                v += resid[(size_t)row * N + col];
                outF[(size_t)row * N + col] = v;
            } else {
                v = fmaxf(v, 0.0f);
                outB[(size_t)row * N + col] = (bf16)v;
            }
        }
    }
}

// ---------------- row LayerNorm over 768: one wave per row (baseline) -------
__global__ __launch_bounds__(256) void ln_k(
        const float* __restrict__ in, float* __restrict__ outF,
        bf16* __restrict__ outB,
        const float* __restrict__ g, const float* __restrict__ b) {
    int wave = threadIdx.x >> 6, lane = threadIdx.x & 63;
    int row = blockIdx.x * 4 + wave;
    const float* xr = in + (size_t)row * DMODEL;
    float4 v[3];
    float s = 0.0f;
#pragma unroll
    for (int j = 0; j < 3; j++) {
        v[j] = *(const float4*)&xr[lane * 4 + 256 * j];
        s += v[j].x + v[j].y + v[j].z + v[j].w;
    }
#pragma unroll
    for (int mk = 1; mk < 64; mk <<= 1) s += __shfl_xor(s, mk, 64);
    float m = s * (1.0f / 768.0f);
    float sq = 0.0f;
#pragma unroll
    for (int j = 0; j < 3; j++) {
        v[j].x -= m; v[j].y -= m; v[j].z -= m; v[j].w -= m;
        sq += v[j].x * v[j].x + v[j].y * v[j].y + v[j].z * v[j].z + v[j].w * v[j].w;
    }
#pragma unroll
    for (int mk = 1; mk < 64; mk <<= 1) sq += __shfl_xor(sq, mk, 64);
    float r = rsqrtf(sq * (1.0f / 768.0f) + 1e-5f);
    float* orow = outF + (size_t)row * DMODEL;
    bf16* brow = outB + (size_t)row * DMODEL;
#pragma unroll
    for (int j = 0; j < 3; j++) {
        int c = lane * 4 + 256 * j;
        float4 gg = *(const float4*)&g[c];
        float4 bb = *(const float4*)&b[c];
        float o0 = v[j].x * r * gg.x + bb.x;
        float o1 = v[j].y * r * gg.y + bb.y;
        float o2 = v[j].z * r * gg.z + bb.z;
        float o3 = v[j].w * r * gg.w + bb.w;
        *(float4*)&orow[c] = make_float4(o0, o1, o2, o3);
        bf16 tmp4[4] = {(bf16)o0, (bf16)o1, (bf16)o2, (bf16)o3};
        *(uint2*)&brow[c] = *(uint2*)tmp4;
    }
}

// ---------------- causal linear attention: 96 blocks (x3 PV split) ----------
// (b,h) = blockIdx/3, nc-range = (blockIdx%3)*4..+3.  QK^T redone per part
// (cheap); PV cols split 3x for CU coverage.  Verified numerically R8/R9.
__global__ __launch_bounds__(320) void attn_k(
        const bf16* __restrict__ qkvB, bf16* __restrict__ att) {
    __shared__ __attribute__((aligned(16))) char smem[64000];
    bf16* Qs = (bf16*)smem;            // [80][200]
    bf16* Ks = (bf16*)(smem + 32000);  // [80][200]
    bf16* Aij = (bf16*)smem;           // [80][104]  (overlays Qs after phase 1)
    bf16* VT = (bf16*)(smem + 16640);  // [192][104] (overlays Ks)
    int bh = blockIdx.x / 3, part = blockIdx.x % 3;
    int bb = bh >> 2, hd = bh & 3;
    int tid = threadIdx.x;
    int w = tid >> 6, l = tid & 63;
    int lm = l & 15, lq = l >> 4;

    uint4 vreg[6];
#pragma unroll
    for (int u = 0; u < 6; u++) {
        int c = tid + 320 * u;
        int t = c / 24, cc = c % 24;
        int d0 = cc * 8;
        size_t g = (size_t)(t * 8 + bb) * NQKV + hd * DH + d0;
        uint4 qv = *(const uint4*)&qkvB[g];
        uint4 kv = *(const uint4*)&qkvB[g + 768];
        vreg[u]  = *(const uint4*)&qkvB[g + 1536];
        *(uint4*)&Qs[t * 200 + d0] = qv;
        *(uint4*)&Ks[t * 200 + d0] = kv;
    }
    __syncthreads();

    f32x4 acc[5] = {};
#pragma unroll
    for (int k0 = 0; k0 < 192; k0 += 32) {
        bf16x8 af = *(bf16x8*)&Qs[(w * 16 + lm) * 200 + lq * 8 + k0];
#pragma unroll
        for (int nb = 0; nb < 5; nb++) {
            bf16x8 bfr = *(bf16x8*)&Ks[(nb * 16 + lm) * 200 + lq * 8 + k0];
            acc[nb] = __builtin_amdgcn_mfma_f32_16x16x32_bf16(af, bfr, acc[nb], 0, 0, 0);
        }
    }
    float mval[5][4];
    float rs[4] = {0.f, 0.f, 0.f, 0.f};
#pragma unroll
    for (int nb = 0; nb < 5; nb++)
#pragma unroll
        for (int r = 0; r < 4; r++) {
            int t = w * 16 + lq * 4 + r, tau = nb * 16 + lm;
            float v = (tau <= t) ? acc[nb][r] : 0.0f;
            mval[nb][r] = v;
            rs[r] += v;
        }
#pragma unroll
    for (int mk = 1; mk < 16; mk <<= 1)
#pragma unroll
        for (int r = 0; r < 4; r++) rs[r] += __shfl_xor(rs[r], mk, 64);
    float inv[4];
#pragma unroll
    for (int r = 0; r < 4; r++) inv[r] = 1.0f / (rs[r] + 1e-6f);

    __syncthreads();

#pragma unroll
    for (int nb = 0; nb < 5; nb++)
#pragma unroll
        for (int r = 0; r < 4; r++)
            Aij[(w * 16 + lq * 4 + r) * 104 + nb * 16 + lm] = (bf16)mval[nb][r];
    *(uint2*)&Aij[(tid >> 2) * 104 + 80 + (tid & 3) * 4] = make_uint2(0u, 0u);
#pragma unroll
    for (int u = 0; u < 6; u++) {
        int c = tid + 320 * u;
        int t = c / 24, cc = c % 24;
        int d0 = cc * 8;
        bf16 tmp8[8];
        *(uint4*)tmp8 = vreg[u];
#pragma unroll
        for (int j = 0; j < 8; j++) VT[(d0 + j) * 104 + t] = tmp8[j];
    }
    if (tid < 192) {
        *(uint4*)&VT[tid * 104 + 80] = make_uint4(0u, 0u, 0u, 0u);
        *(uint4*)&VT[tid * 104 + 88] = make_uint4(0u, 0u, 0u, 0u);
    }
    __syncthreads();

#pragma unroll 1
    for (int nc = part * 4; nc < part * 4 + 4; nc++) {
        f32x4 a2 = {};
#pragma unroll
        for (int k0 = 0; k0 < 96; k0 += 32) {
            bf16x8 af = *(bf16x8*)&Aij[(w * 16 + lm) * 104 + lq * 8 + k0];
            bf16x8 bfr = *(bf16x8*)&VT[(nc * 16 + lm) * 104 + lq * 8 + k0];
            a2 = __builtin_amdgcn_mfma_f32_16x16x32_bf16(af, bfr, a2, 0, 0, 0);
        }
#pragma unroll
        for (int r = 0; r < 4; r++) {
            int t = w * 16 + lq * 4 + r;
            att[(size_t)(t * 8 + bb) * DMODEL + hd * DH + nc * 16 + lm] =
                (bf16)(a2[r] * inv[r]);
        }
    }
}

// ---------------- final LN + output gather (baseline) ----------------
__global__ __launch_bounds__(256) void final_k(
        const float* __restrict__ h, const int* __restrict__ act_ts,
        const float* __restrict__ g, const float* __restrict__ bb,
        float* __restrict__ out) {
    __shared__ float sm4[4];
    int ba = blockIdx.x;
    int b = ba / NA;
    int ts = act_ts[ba];
    int t = ts - 1; if (t < 0) t = 0;
    const float* xr = h + (size_t)(t * 8 + b) * DMODEL;
    int c = threadIdx.x;
    float x0 = xr[c], x1 = xr[c + 256], x2 = xr[c + 512];
    float m = block_reduce_sum256(x0 + x1 + x2, sm4) * (1.0f / 768.0f);
    float d0 = x0 - m, d1 = x1 - m, d2 = x2 - m;
    float v = block_reduce_sum256(d0 * d0 + d1 * d1 + d2 * d2, sm4) * (1.0f / 768.0f);
    float r = rsqrtf(v + 1e-5f);
    out[ba * 256 + c]            = d0 * r * g[c] + bb[c];                 // mu
    out[48 * 256 + ba * 256 + c] = d1 * r * g[c + 256] + bb[c + 256];     // logvar
}

extern "C" void kernel_launch(void* const* d_in, const int* in_sizes, int n_in,
                              void* d_out, int out_size, void* d_ws, size_t ws_size,
                              hipStream_t stream) {
    const float* x       = (const float*)d_in[0];
    const int*   y       = (const int*)d_in[1];
    const int*   ind_map = (const int*)d_in[2];
    const int*   act_ts  = (const int*)d_in[3];
    const float* skel_W  = (const float*)d_in[4];
    const float* skel_b  = (const float*)d_in[5];
    const float* muQ     = (const float*)d_in[6];
    const float* sigQ    = (const float*)d_in[7];
    const float* Wq = (const float*)d_in[8];   const float* bq = (const float*)d_in[9];
    const float* Wk = (const float*)d_in[10];  const float* bk = (const float*)d_in[11];
    const float* Wv = (const float*)d_in[12];  const float* bv = (const float*)d_in[13];
    const float* Wo = (const float*)d_in[14];  const float* bo = (const float*)d_in[15];
    const float* W1 = (const float*)d_in[16];  const float* b1 = (const float*)d_in[17];
    const float* W2 = (const float*)d_in[18];  const float* b2 = (const float*)d_in[19];
    const float* ln1_g = (const float*)d_in[20]; const float* ln1_b = (const float*)d_in[21];
    const float* ln2_g = (const float*)d_in[22]; const float* ln2_b = (const float*)d_in[23];
    const float* lnf_g = (const float*)d_in[24]; const float* lnf_b = (const float*)d_in[25];
    float* out = (float*)d_out;

    // ---- workspace layout (all 16B aligned) — identical to baseline ----
    char* p = (char*)d_ws;
    const size_t R  = (size_t)NROWS * DMODEL;      // 491520
    float* h    = (float*)p; p += R * 4;
    float* h1   = (float*)p; p += R * 4;
    float* tmp  = (float*)p; p += R * 4;
    bf16* qkvB  = (bf16*)p;  p += (size_t)NROWS * NQKV * 2;
    bf16* hB    = (bf16*)p;  p += R * 2;
    bf16* h1B   = (bf16*)p;  p += R * 2;
    bf16* attB  = (bf16*)p;  p += R * 2;
    bf16* ffn1B = (bf16*)p;  p += (size_t)NROWS * FFD * 2;
    bf16* qkvT  = (bf16*)p;  p += (size_t)4 * NQKV * DMODEL * 2;
    bf16* woT   = (bf16*)p;  p += (size_t)4 * DMODEL * DMODEL * 2;
    bf16* w1T   = (bf16*)p;  p += (size_t)4 * FFD * DMODEL * 2;
    bf16* w2T   = (bf16*)p;  p += (size_t)4 * DMODEL * FFD * 2;

    // merged transpose + embed (one dispatch, verified R8/R9)
    prep_k<<<16000, 256, 0, stream>>>(x, y, ind_map, skel_W, skel_b, muQ, sigQ,
                                      Wq, Wk, Wv, Wo, W1, W2,
                                      qkvT, woT, w1T, w2T, h, hB);

    dim3 gQKV(NQKV / 64, 10);
    dim3 g768(12, 10);
    dim3 g1024(16, 10);
    for (int l = 0; l < 4; l++) {
        const bf16* qkvTl = qkvT + (size_t)l * NQKV * DMODEL;
        const bf16* woTl  = woT  + (size_t)l * DMODEL * DMODEL;
        const bf16* w1Tl  = w1T  + (size_t)l * FFD * DMODEL;
        const bf16* w2Tl  = w2T  + (size_t)l * DMODEL * FFD;
        // QKV fused: [640,768] @ [768,2304] -> qkvB bf16 (elu+1 on Q,K)
        gemm_mfma<0><<<gQKV, 256, 0, stream>>>(hB, qkvTl,
                bq + l * DMODEL, bk + l * DMODEL, bv + l * DMODEL,
                nullptr, nullptr, qkvB, NROWS, NQKV, DMODEL);
        attn_k<<<96, 320, 0, stream>>>(qkvB, attB);
        // att @ Wo + bo + h -> tmp
        gemm_mfma<1><<<g768, 256, 0, stream>>>(attB, woTl,
                bo + l * DMODEL, nullptr, nullptr, h, tmp, nullptr,
                NROWS, DMODEL, DMODEL);
        ln_k<<<NROWS / 4, 256, 0, stream>>>(tmp, h1, h1B, ln1_g + l * DMODEL, ln1_b + l * DMODEL);
        // relu(h1 @ W1 + b1) -> ffn1 (bf16)
        gemm_mfma<2><<<g1024, 256, 0, stream>>>(h1B, w1Tl,
                b1 + l * FFD, nullptr, nullptr, nullptr, nullptr, ffn1B,
                NROWS, FFD, DMODEL);
        // ffn1 @ W2 + b2 + h1 -> tmp
        gemm_mfma<1><<<g768, 256, 0, stream>>>(ffn1B, w2Tl,
                b2 + l * DMODEL, nullptr, nullptr, h1, tmp, nullptr,
                NROWS, DMODEL, FFD);
        ln_k<<<NROWS / 4, 256, 0, stream>>>(tmp, h, hB, ln2_g + l * DMODEL, ln2_b + l * DMODEL);
    }

    final_k<<<48, 256, 0, stream>>>(h, act_ts, lnf_g, lnf_b, out);
}

// Round 11
// 402.578 us; speedup vs baseline: 1.1365x; 1.0403x over previous
//
#include <hip/hip_runtime.h>
#include <math.h>

// Problem constants
#define TT 80
#define BS 8
#define NA 6
#define DMODEL 768
#define NH 4
#define DH 192
#define FFD 1024
#define NROWS (TT*BS)   // 640
#define NQKV (3*DMODEL) // 2304

typedef __bf16 bf16;
typedef __bf16 bf16x8 __attribute__((ext_vector_type(8)));
typedef float  f32x4  __attribute__((ext_vector_type(4)));

// ---------------- block reduce (256 threads, 4 waves of 64) ----------------
__device__ __forceinline__ float block_reduce_sum256(float v, float* sm4) {
#pragma unroll
    for (int off = 32; off > 0; off >>= 1) v += __shfl_down(v, off, 64);
    int lane = threadIdx.x & 63, wid = threadIdx.x >> 6;
    if (lane == 0) sm4[wid] = v;
    __syncthreads();
    float r = sm4[0] + sm4[1] + sm4[2] + sm4[3];
    __syncthreads();
    return r;
}

// ---------------- prep: ALL weight transposes + embedding (one dispatch) ----
// blocks 0..15359: one 32x32 transpose tile each (decode verified R2..R10).
// blocks 15360..15999: embedding row r = t*8+b.
__global__ __launch_bounds__(256) void prep_k(
        const float* __restrict__ x, const int* __restrict__ y,
        const int* __restrict__ ind_map,
        const float* __restrict__ skel_W, const float* __restrict__ skel_b,
        const float* __restrict__ muQ, const float* __restrict__ sigQ,
        const float* __restrict__ Wq, const float* __restrict__ Wk,
        const float* __restrict__ Wv, const float* __restrict__ Wo,
        const float* __restrict__ W1, const float* __restrict__ W2,
        bf16* __restrict__ qkvT, bf16* __restrict__ woT,
        bf16* __restrict__ w1T, bf16* __restrict__ w2T,
        float* __restrict__ h0, bf16* __restrict__ h0b) {
    __shared__ float tile[32][33];
    __shared__ float xrow[152];
    int bid = blockIdx.x, tid = threadIdx.x;
    if (bid < 15360) {
        const float* src; bf16* dst; int ldsrc, Kd, n0, k0;
        int l = bid / 3840, r = bid % 3840;
        if (r < 1728) {                             // QKV: K=768, N=2304
            int kt = r % 24, nt = r / 24;
            k0 = kt * 32; n0 = nt * 32; Kd = 768; ldsrc = 768;
            dst = qkvT + (size_t)l * NQKV * DMODEL;
            if (n0 < 768)       { src = Wq + (size_t)l * 589824 + n0; }
            else if (n0 < 1536) { src = Wk + (size_t)l * 589824 + (n0 - 768); }
            else                { src = Wv + (size_t)l * 589824 + (n0 - 1536); }
        } else if (r < 2304) {                      // Wo: 768x768
            int r2 = r - 1728; int kt = r2 % 24, nt = r2 / 24;
            k0 = kt * 32; n0 = nt * 32; Kd = 768; ldsrc = 768;
            src = Wo + (size_t)l * 589824 + n0;
            dst = woT + (size_t)l * 589824;
        } else if (r < 3072) {                      // W1: K=768, N=1024
            int r2 = r - 2304; int kt = r2 % 24, nt = r2 / 24;
            k0 = kt * 32; n0 = nt * 32; Kd = 768; ldsrc = 1024;
            src = W1 + (size_t)l * 786432 + n0;
            dst = w1T + (size_t)l * 786432;
        } else {                                    // W2: K=1024, N=768
            int r2 = r - 3072; int kt = r2 % 32, nt = r2 / 32;
            k0 = kt * 32; n0 = nt * 32; Kd = 1024; ldsrc = 768;
            src = W2 + (size_t)l * 786432 + n0;
            dst = w2T + (size_t)l * 786432;
        }
        int tx = tid & 31, ty = tid >> 5;
#pragma unroll
        for (int i = 0; i < 4; i++) {
            int rr = ty + 8 * i;
            tile[rr][tx] = src[(size_t)(k0 + rr) * ldsrc + tx];
        }
        __syncthreads();
#pragma unroll
        for (int i = 0; i < 4; i++) {
            int rr = ty + 8 * i;
            dst[(size_t)(n0 + rr) * Kd + k0 + tx] = (bf16)tile[tx][rr];
        }
    } else {
        int r = bid - 15360;
        int t = r >> 3, b = r & 7;
        int c = tid;
        if (c < 150) xrow[c] = x[(b * 150 + c) * TT + t];
        __syncthreads();
        float acc = skel_b[c];
        for (int jf = 0; jf < 150; jf++) acc += xrow[jf] * skel_W[jf * 256 + c];
        int ind_t = ind_map[t * 8 + b];
        int yb = y[b * NA + ind_t];
        float cm = muQ[yb * 256 + c];
        float cs = sigQ[yb * 256 + c];
        int start = (t == 0) ? 0 : (t + 2);
        float div = expf((float)(c & ~1) * (-9.210340371976184f / 256.0f));
        float p0, p1, p2;
        if (c & 1) {
            p0 = cosf((float)start * div);
            p1 = cosf((float)(start + 1) * div);
            p2 = cosf((float)(start + 2) * div);
        } else {
            p0 = sinf((float)start * div);
            p1 = sinf((float)(start + 1) * div);
            p2 = sinf((float)(start + 2) * div);
        }
        float* hr = h0 + (size_t)r * DMODEL;
        float v0 = cm + p0, v1 = cs + p1, v2 = acc + p2;
        hr[c] = v0; hr[c + 256] = v1; hr[c + 512] = v2;
        bf16* hb = h0b + (size_t)r * DMODEL;
        hb[c] = (bf16)v0; hb[c + 256] = (bf16)v1; hb[c + 512] = (bf16)v2;
    }
}

// ---------------- bf16 MFMA GEMM: 64x64 tile, global_load_lds staging -------
// Double-buffered async DMA staging (m151: +35% vs reg-staging at this scale):
// one __syncthreads per K-64 step (its implicit vmcnt(0) drain IS the wait for
// the chunk issued last iteration); next chunk's DMA issued right after the
// barrier so it lands during this chunk's MFMAs.
// LDS layout: unpadded [64][64] (DMA dest = wave base + lane*16, linear) with
// XOR-swizzle chunk' = chunk ^ (row&7) applied on the GLOBAL SOURCE address
// (per-lane) and on the READ offset (rule: both-sides-or-neither).
// A [M,K] row-major bf16; Bt [N,K] row-major bf16.  K % 64 == 0.
// EPI: 0 = QKV (bias by col segment, elu+1 on cols<1536, bf16 out)
//      1 = bias + f32 resid, f32 out
//      2 = bias + relu, bf16 out
template <int EPI>
__global__ __launch_bounds__(256) void gemm_mfma(
        const bf16* __restrict__ A, const bf16* __restrict__ Bt,
        const float* __restrict__ bias_q, const float* __restrict__ bias_k,
        const float* __restrict__ bias_v, const float* __restrict__ resid,
        float* __restrict__ outF, bf16* __restrict__ outB,
        int M, int N, int K) {
    __shared__ __attribute__((aligned(16))) bf16 As[2][64][64];
    __shared__ __attribute__((aligned(16))) bf16 Bs[2][64][64];
    int tid = threadIdx.x;
    int m0 = blockIdx.y * 64, n0 = blockIdx.x * 64;
    int w = tid >> 6;
    int l = tid & 63;
    int lm = l & 15, lq = l >> 4;
    int srow = l >> 3;                 // 0..7 (row within each 8-row DMA group)
    int sch  = (l & 7) ^ srow;         // pre-swizzled source chunk (bijective)
    // per-lane global bases; +off walks K in 64-element chunks
    const bf16* Ar0 = &A [(size_t)(m0 + w * 16 +     srow) * K + sch * 8];
    const bf16* Ar1 = &A [(size_t)(m0 + w * 16 + 8 + srow) * K + sch * 8];
    const bf16* Br0 = &Bt[(size_t)(n0 + w * 16 +     srow) * K + sch * 8];
    const bf16* Br1 = &Bt[(size_t)(n0 + w * 16 + 8 + srow) * K + sch * 8];
    f32x4 acc[4] = {};
    int nch = K >> 6;
    int xk = (lm & 7) * 8;             // XOR read key, premultiplied (bf16 idx)
    // prologue: chunk 0 -> buf 0 (4 DMA issues per thread)
    __builtin_amdgcn_global_load_lds(Ar0, &As[0][w * 16][0],     16, 0, 0);
    __builtin_amdgcn_global_load_lds(Ar1, &As[0][w * 16 + 8][0], 16, 0, 0);
    __builtin_amdgcn_global_load_lds(Br0, &Bs[0][w * 16][0],     16, 0, 0);
    __builtin_amdgcn_global_load_lds(Br1, &Bs[0][w * 16 + 8][0], 16, 0, 0);
    for (int i = 0; i < nch; i++) {
        int cur = i & 1;
        __syncthreads();               // vmcnt(0) drain: chunk i resident, all waves joined
        if (i + 1 < nch) {             // issue next chunk into the other buffer
            int off = (i + 1) << 6;
            int nb2 = cur ^ 1;
            __builtin_amdgcn_global_load_lds(Ar0 + off, &As[nb2][w * 16][0],     16, 0, 0);
            __builtin_amdgcn_global_load_lds(Ar1 + off, &As[nb2][w * 16 + 8][0], 16, 0, 0);
            __builtin_amdgcn_global_load_lds(Br0 + off, &Bs[nb2][w * 16][0],     16, 0, 0);
            __builtin_amdgcn_global_load_lds(Br1 + off, &Bs[nb2][w * 16 + 8][0], 16, 0, 0);
        }
        int r = w * 16 + lm;
        bf16x8 af0 = *(bf16x8*)&As[cur][r][(lq * 8) ^ xk];
        bf16x8 af1 = *(bf16x8*)&As[cur][r][((4 + lq) * 8) ^ xk];
#pragma unroll
        for (int nb = 0; nb < 4; nb++) {
            bf16x8 bf0 = *(bf16x8*)&Bs[cur][nb * 16 + lm][(lq * 8) ^ xk];
            acc[nb] = __builtin_amdgcn_mfma_f32_16x16x32_bf16(af0, bf0, acc[nb], 0, 0, 0);
        }
#pragma unroll
        for (int nb = 0; nb < 4; nb++) {
            bf16x8 bf1 = *(bf16x8*)&Bs[cur][nb * 16 + lm][((4 + lq) * 8) ^ xk];
            acc[nb] = __builtin_amdgcn_mfma_f32_16x16x32_bf16(af1, bf1, acc[nb], 0, 0, 0);
        }
    }
#pragma unroll
    for (int nb = 0; nb < 4; nb++) {
        int col = n0 + nb * 16 + lm;
        float b;
        bool do_elu = false;
        if (EPI == 0) {
            if (col < 768)       { b = bias_q[col];        do_elu = true; }
            else if (col < 1536) { b = bias_k[col - 768];  do_elu = true; }
            else                 { b = bias_v[col - 1536]; }
        } else {
            b = bias_q[col];
        }
#pragma unroll
        for (int r = 0; r < 4; r++) {
            int row = m0 + w * 16 + lq * 4 + r;
            float v = acc[nb][r] + b;
            if (EPI == 0) {
                if (do_elu) v = (v > 0.0f) ? (v + 1.0f) : expf(v);
                outB[(size_t)row * N + col] = (bf16)v;
            } else if (EPI == 1) {
                v += resid[(size_t)row * N + col];
                outF[(size_t)row * N + col] = v;
            } else {
                v = fmaxf(v, 0.0f);
                outB[(size_t)row * N + col] = (bf16)v;
            }
        }
    }
}

// ---------------- row LayerNorm over 768: one wave per row (baseline) -------
__global__ __launch_bounds__(256) void ln_k(
        const float* __restrict__ in, float* __restrict__ outF,
        bf16* __restrict__ outB,
        const float* __restrict__ g, const float* __restrict__ b) {
    int wave = threadIdx.x >> 6, lane = threadIdx.x & 63;
    int row = blockIdx.x * 4 + wave;
    const float* xr = in + (size_t)row * DMODEL;
    float4 v[3];
    float s = 0.0f;
#pragma unroll
    for (int j = 0; j < 3; j++) {
        v[j] = *(const float4*)&xr[lane * 4 + 256 * j];
        s += v[j].x + v[j].y + v[j].z + v[j].w;
    }
#pragma unroll
    for (int mk = 1; mk < 64; mk <<= 1) s += __shfl_xor(s, mk, 64);
    float m = s * (1.0f / 768.0f);
    float sq = 0.0f;
#pragma unroll
    for (int j = 0; j < 3; j++) {
        v[j].x -= m; v[j].y -= m; v[j].z -= m; v[j].w -= m;
        sq += v[j].x * v[j].x + v[j].y * v[j].y + v[j].z * v[j].z + v[j].w * v[j].w;
    }
#pragma unroll
    for (int mk = 1; mk < 64; mk <<= 1) sq += __shfl_xor(sq, mk, 64);
    float r = rsqrtf(sq * (1.0f / 768.0f) + 1e-5f);
    float* orow = outF + (size_t)row * DMODEL;
    bf16* brow = outB + (size_t)row * DMODEL;
#pragma unroll
    for (int j = 0; j < 3; j++) {
        int c = lane * 4 + 256 * j;
        float4 gg = *(const float4*)&g[c];
        float4 bb = *(const float4*)&b[c];
        float o0 = v[j].x * r * gg.x + bb.x;
        float o1 = v[j].y * r * gg.y + bb.y;
        float o2 = v[j].z * r * gg.z + bb.z;
        float o3 = v[j].w * r * gg.w + bb.w;
        *(float4*)&orow[c] = make_float4(o0, o1, o2, o3);
        bf16 tmp4[4] = {(bf16)o0, (bf16)o1, (bf16)o2, (bf16)o3};
        *(uint2*)&brow[c] = *(uint2*)tmp4;
    }
}

// ---------------- causal linear attention: 96 blocks (x3 PV split) ----------
// (b,h) = blockIdx/3, nc-range = (blockIdx%3)*4..+3.  Verified R8..R10.
__global__ __launch_bounds__(320) void attn_k(
        const bf16* __restrict__ qkvB, bf16* __restrict__ att) {
    __shared__ __attribute__((aligned(16))) char smem[64000];
    bf16* Qs = (bf16*)smem;            // [80][200]
    bf16* Ks = (bf16*)(smem + 32000);  // [80][200]
    bf16* Aij = (bf16*)smem;           // [80][104]  (overlays Qs after phase 1)
    bf16* VT = (bf16*)(smem + 16640);  // [192][104] (overlays Ks)
    int bh = blockIdx.x / 3, part = blockIdx.x % 3;
    int bb = bh >> 2, hd = bh & 3;
    int tid = threadIdx.x;
    int w = tid >> 6, l = tid & 63;
    int lm = l & 15, lq = l >> 4;

    uint4 vreg[6];
#pragma unroll
    for (int u = 0; u < 6; u++) {
        int c = tid + 320 * u;
        int t = c / 24, cc = c % 24;
        int d0 = cc * 8;
        size_t g = (size_t)(t * 8 + bb) * NQKV + hd * DH + d0;
        uint4 qv = *(const uint4*)&qkvB[g];
        uint4 kv = *(const uint4*)&qkvB[g + 768];
        vreg[u]  = *(const uint4*)&qkvB[g + 1536];
        *(uint4*)&Qs[t * 200 + d0] = qv;
        *(uint4*)&Ks[t * 200 + d0] = kv;
    }
    __syncthreads();

    f32x4 acc[5] = {};
#pragma unroll
    for (int k0 = 0; k0 < 192; k0 += 32) {
        bf16x8 af = *(bf16x8*)&Qs[(w * 16 + lm) * 200 + lq * 8 + k0];
#pragma unroll
        for (int nb = 0; nb < 5; nb++) {
            bf16x8 bfr = *(bf16x8*)&Ks[(nb * 16 + lm) * 200 + lq * 8 + k0];
            acc[nb] = __builtin_amdgcn_mfma_f32_16x16x32_bf16(af, bfr, acc[nb], 0, 0, 0);
        }
    }
    float mval[5][4];
    float rs[4] = {0.f, 0.f, 0.f, 0.f};
#pragma unroll
    for (int nb = 0; nb < 5; nb++)
#pragma unroll
        for (int r = 0; r < 4; r++) {
            int t = w * 16 + lq * 4 + r, tau = nb * 16 + lm;
            float v = (tau <= t) ? acc[nb][r] : 0.0f;
            mval[nb][r] = v;
            rs[r] += v;
        }
#pragma unroll
    for (int mk = 1; mk < 16; mk <<= 1)
#pragma unroll
        for (int r = 0; r < 4; r++) rs[r] += __shfl_xor(rs[r], mk, 64);
    float inv[4];
#pragma unroll
    for (int r = 0; r < 4; r++) inv[r] = 1.0f / (rs[r] + 1e-6f);

    __syncthreads();

#pragma unroll
    for (int nb = 0; nb < 5; nb++)
#pragma unroll
        for (int r = 0; r < 4; r++)
            Aij[(w * 16 + lq * 4 + r) * 104 + nb * 16 + lm] = (bf16)mval[nb][r];
    *(uint2*)&Aij[(tid >> 2) * 104 + 80 + (tid & 3) * 4] = make_uint2(0u, 0u);
#pragma unroll
    for (int u = 0; u < 6; u++) {
        int c = tid + 320 * u;
        int t = c / 24, cc = c % 24;
        int d0 = cc * 8;
        bf16 tmp8[8];
        *(uint4*)tmp8 = vreg[u];
#pragma unroll
        for (int j = 0; j < 8; j++) VT[(d0 + j) * 104 + t] = tmp8[j];
    }
    if (tid < 192) {
        *(uint4*)&VT[tid * 104 + 80] = make_uint4(0u, 0u, 0u, 0u);
        *(uint4*)&VT[tid * 104 + 88] = make_uint4(0u, 0u, 0u, 0u);
    }
    __syncthreads();

#pragma unroll 1
    for (int nc = part * 4; nc < part * 4 + 4; nc++) {
        f32x4 a2 = {};
#pragma unroll
        for (int k0 = 0; k0 < 96; k0 += 32) {
            bf16x8 af = *(bf16x8*)&Aij[(w * 16 + lm) * 104 + lq * 8 + k0];
            bf16x8 bfr = *(bf16x8*)&VT[(nc * 16 + lm) * 104 + lq * 8 + k0];
            a2 = __builtin_amdgcn_mfma_f32_16x16x32_bf16(af, bfr, a2, 0, 0, 0);
        }
#pragma unroll
        for (int r = 0; r < 4; r++) {
            int t = w * 16 + lq * 4 + r;
            att[(size_t)(t * 8 + bb) * DMODEL + hd * DH + nc * 16 + lm] =
                (bf16)(a2[r] * inv[r]);
        }
    }
}

// ---------------- final LN + output gather (baseline) ----------------
__global__ __launch_bounds__(256) void final_k(
        const float* __restrict__ h, const int* __restrict__ act_ts,
        const float* __restrict__ g, const float* __restrict__ bb,
        float* __restrict__ out) {
    __shared__ float sm4[4];
    int ba = blockIdx.x;
    int b = ba / NA;
    int ts = act_ts[ba];
    int t = ts - 1; if (t < 0) t = 0;
    const float* xr = h + (size_t)(t * 8 + b) * DMODEL;
    int c = threadIdx.x;
    float x0 = xr[c], x1 = xr[c + 256], x2 = xr[c + 512];
    float m = block_reduce_sum256(x0 + x1 + x2, sm4) * (1.0f / 768.0f);
    float d0 = x0 - m, d1 = x1 - m, d2 = x2 - m;
    float v = block_reduce_sum256(d0 * d0 + d1 * d1 + d2 * d2, sm4) * (1.0f / 768.0f);
    float r = rsqrtf(v + 1e-5f);
    out[ba * 256 + c]            = d0 * r * g[c] + bb[c];                 // mu
    out[48 * 256 + ba * 256 + c] = d1 * r * g[c + 256] + bb[c + 256];     // logvar
}

extern "C" void kernel_launch(void* const* d_in, const int* in_sizes, int n_in,
                              void* d_out, int out_size, void* d_ws, size_t ws_size,
                              hipStream_t stream) {
    const float* x       = (const float*)d_in[0];
    const int*   y       = (const int*)d_in[1];
    const int*   ind_map = (const int*)d_in[2];
    const int*   act_ts  = (const int*)d_in[3];
    const float* skel_W  = (const float*)d_in[4];
    const float* skel_b  = (const float*)d_in[5];
    const float* muQ     = (const float*)d_in[6];
    const float* sigQ    = (const float*)d_in[7];
    const float* Wq = (const float*)d_in[8];   const float* bq = (const float*)d_in[9];
    const float* Wk = (const float*)d_in[10];  const float* bk = (const float*)d_in[11];
    const float* Wv = (const float*)d_in[12];  const float* bv = (const float*)d_in[13];
    const float* Wo = (const float*)d_in[14];  const float* bo = (const float*)d_in[15];
    const float* W1 = (const float*)d_in[16];  const float* b1 = (const float*)d_in[17];
    const float* W2 = (const float*)d_in[18];  const float* b2 = (const float*)d_in[19];
    const float* ln1_g = (const float*)d_in[20]; const float* ln1_b = (const float*)d_in[21];
    const float* ln2_g = (const float*)d_in[22]; const float* ln2_b = (const float*)d_in[23];
    const float* lnf_g = (const float*)d_in[24]; const float* lnf_b = (const float*)d_in[25];
    float* out = (float*)d_out;

    // ---- workspace layout (all 16B aligned) — identical to baseline ----
    char* p = (char*)d_ws;
    const size_t R  = (size_t)NROWS * DMODEL;      // 491520
    float* h    = (float*)p; p += R * 4;
    float* h1   = (float*)p; p += R * 4;
    float* tmp  = (float*)p; p += R * 4;
    bf16* qkvB  = (bf16*)p;  p += (size_t)NROWS * NQKV * 2;
    bf16* hB    = (bf16*)p;  p += R * 2;
    bf16* h1B   = (bf16*)p;  p += R * 2;
    bf16* attB  = (bf16*)p;  p += R * 2;
    bf16* ffn1B = (bf16*)p;  p += (size_t)NROWS * FFD * 2;
    bf16* qkvT  = (bf16*)p;  p += (size_t)4 * NQKV * DMODEL * 2;
    bf16* woT   = (bf16*)p;  p += (size_t)4 * DMODEL * DMODEL * 2;
    bf16* w1T   = (bf16*)p;  p += (size_t)4 * FFD * DMODEL * 2;
    bf16* w2T   = (bf16*)p;  p += (size_t)4 * DMODEL * FFD * 2;

    // merged transpose + embed (one dispatch, verified R8..R10)
    prep_k<<<16000, 256, 0, stream>>>(x, y, ind_map, skel_W, skel_b, muQ, sigQ,
                                      Wq, Wk, Wv, Wo, W1, W2,
                                      qkvT, woT, w1T, w2T, h, hB);

    dim3 gQKV(NQKV / 64, 10);
    dim3 g768(12, 10);
    dim3 g1024(16, 10);
    for (int l = 0; l < 4; l++) {
        const bf16* qkvTl = qkvT + (size_t)l * NQKV * DMODEL;
        const bf16* woTl  = woT  + (size_t)l * DMODEL * DMODEL;
        const bf16* w1Tl  = w1T  + (size_t)l * FFD * DMODEL;
        const bf16* w2Tl  = w2T  + (size_t)l * DMODEL * FFD;
        // QKV fused: [640,768] @ [768,2304] -> qkvB bf16 (elu+1 on Q,K)
        gemm_mfma<0><<<gQKV, 256, 0, stream>>>(hB, qkvTl,
                bq + l * DMODEL, bk + l * DMODEL, bv + l * DMODEL,
                nullptr, nullptr, qkvB, NROWS, NQKV, DMODEL);
        attn_k<<<96, 320, 0, stream>>>(qkvB, attB);
        // att @ Wo + bo + h -> tmp
        gemm_mfma<1><<<g768, 256, 0, stream>>>(attB, woTl,
                bo + l * DMODEL, nullptr, nullptr, h, tmp, nullptr,
                NROWS, DMODEL, DMODEL);
        ln_k<<<NROWS / 4, 256, 0, stream>>>(tmp, h1, h1B, ln1_g + l * DMODEL, ln1_b + l * DMODEL);
        // relu(h1 @ W1 + b1) -> ffn1 (bf16)
        gemm_mfma<2><<<g1024, 256, 0, stream>>>(h1B, w1Tl,
                b1 + l * FFD, nullptr, nullptr, nullptr, nullptr, ffn1B,
                NROWS, FFD, DMODEL);
        // ffn1 @ W2 + b2 + h1 -> tmp
        gemm_mfma<1><<<g768, 256, 0, stream>>>(ffn1B, w2Tl,
                b2 + l * DMODEL, nullptr, nullptr, h1, tmp, nullptr,
                NROWS, DMODEL, FFD);
        ln_k<<<NROWS / 4, 256, 0, stream>>>(tmp, h, hB, ln2_g + l * DMODEL, ln2_b + l * DMODEL);
    }

    final_k<<<48, 256, 0, stream>>>(h, act_ts, lnf_g, lnf_b, out);
}